// Round 11
// baseline (31.498 us; speedup 1.0000x reference)
//
#include <hip/hip_runtime.h>

// out[b,c,y,x] = sum_{i,j} Dot[b,3i+j,y,x] * V[b,c,y+i-1,x+j-1]  (zero-padded)
// b=16, c=64, h=w=128, fp32. HBM steady-state ~103 MB.
// R3/R7/R8/R10 all pin at 27.8-29.9us (3.6 TB/s, occ ~26%) across different
// structures. Discriminating experiment: same R10 pipeline (V loads first,
// async Dot->LDS, one barrier) but 512-thread blocks x 1024 grid: 8 waves/
// block, ~3 blocks/CU, whole chip resident in one generation. NO min-waves
// bound (R6 lesson: forced VGPR cap -> spills). If still ~28us -> shared
// bandwidth ceiling for L3-read+HBM-write mix -> roofline.

#define HH 128
#define WW 128
#define CC 64
#define KK 9

typedef float f4 __attribute__((ext_vector_type(4)));

__device__ __forceinline__ void accum3(f4& o, float vl, const f4& vm, float vr,
                                       const f4& d0, const f4& d1, const f4& d2)
{
    o.x += d0.x * vl   + d1.x * vm.x + d2.x * vm.y;
    o.y += d0.y * vm.x + d1.y * vm.y + d2.y * vm.z;
    o.z += d0.z * vm.y + d1.z * vm.z + d2.z * vm.w;
    o.w += d0.w * vm.z + d1.w * vm.w + d2.w * vr;
}

__global__ __launch_bounds__(512) void msa_conv2d_kernel(
    const float* __restrict__ Dot,
    const float* __restrict__ V,
    float* __restrict__ out)
{
    __shared__ float dotRow[2][KK][WW];   // 9216 B = 576 x 16B chunks

    // 1024 blocks; XCD = n%8 (round-robin). XCD k owns contiguous chunk
    // [k*128, (k+1)*128) of work ids L = b*64 + yp -> adjacent yp (V halo
    // overlap) and all channels of (b,yp) (Dot reuse) stay on one XCD.
    const int n   = blockIdx.x;
    const int L   = (n & 7) * 128 + (n >> 3);
    const int b   = L >> 6;             // 0..15
    const int yp  = L & 63;             // 0..63
    const int y0  = yp * 2;

    const int tid = threadIdx.x;
    const int tx  = tid & 31;           // x-quad 0..31
    const int tc  = tid >> 5;           // channel sub-index 0..15
    const int x0  = tx * 4;

    const bool topOK = (y0 > 0);
    const bool botOK = (y0 + 2 < HH);
    const f4 z4 = {0.f, 0.f, 0.f, 0.f};

    const float* vB = V   + ((size_t)b * CC) * (HH * WW);
    float*       oB = out + ((size_t)b * CC) * (HH * WW);

    // ---- Phase 1a: issue all 16 V loads (fly during Dot staging + barrier).
    f4 r[4][4];
    #pragma unroll
    for (int cc = 0; cc < 4; ++cc) {
        const int c = cc * 16 + tc;
        const float* vC = vB + (size_t)c * (HH * WW) + x0;
        r[cc][0] = topOK ? *reinterpret_cast<const f4*>(vC + (size_t)(y0 - 1) * WW) : z4;
        r[cc][1] =         *reinterpret_cast<const f4*>(vC + (size_t)(y0    ) * WW);
        r[cc][2] =         *reinterpret_cast<const f4*>(vC + (size_t)(y0 + 1) * WW);
        r[cc][3] = botOK ? *reinterpret_cast<const f4*>(vC + (size_t)(y0 + 2) * WW) : z4;
    }

    // ---- Phase 1b: async-stage Dot[b, 0..8, y0..y0+1, :] straight to LDS.
    // Chunk t in [0,576): flat float idx = 4t = ((yy*9 + k)*128 + x4*4).
    // LDS dest linear in t -> wave-uniform base + lane*16 (layout requirement
    // met; chunks 512..575 are exactly the first wave's 64 lanes).
    {
        float* ldsBase = &dotRow[0][0][0];
        {
            const int t  = tid;
            const int yy = t / 288;
            const int rm = t - yy * 288;
            const int k  = rm >> 5;
            const int x4 = rm & 31;
            const float* src = Dot + (((size_t)b * KK + k) * HH + (y0 + yy)) * WW + x4 * 4;
            __builtin_amdgcn_global_load_lds(
                (const __attribute__((address_space(1))) void*)src,
                (__attribute__((address_space(3))) void*)(ldsBase + (size_t)t * 4),
                16, 0, 0);
        }
        if (tid < 64) {
            const int t  = tid + 512;
            const int yy = t / 288;
            const int rm = t - yy * 288;
            const int k  = rm >> 5;
            const int x4 = rm & 31;
            const float* src = Dot + (((size_t)b * KK + k) * HH + (y0 + yy)) * WW + x4 * 4;
            __builtin_amdgcn_global_load_lds(
                (const __attribute__((address_space(1))) void*)src,
                (__attribute__((address_space(3))) void*)(ldsBase + (size_t)t * 4),
                16, 0, 0);
        }
    }
    __syncthreads();   // one vmcnt drain completes BOTH V loads and staging

    // ---- Phase 2: weights from LDS (broadcast), compute, store.
    f4 dA[KK], dB[KK];
    #pragma unroll
    for (int k = 0; k < KK; ++k) {
        dA[k] = *reinterpret_cast<const f4*>(&dotRow[0][k][x0]);
        dB[k] = *reinterpret_cast<const f4*>(&dotRow[1][k][x0]);
    }

    #pragma unroll
    for (int cc = 0; cc < 4; ++cc) {
        const int c = cc * 16 + tc;

        float l0 = __shfl_up(r[cc][0].w, 1, 32), h0 = __shfl_down(r[cc][0].x, 1, 32);
        float l1 = __shfl_up(r[cc][1].w, 1, 32), h1 = __shfl_down(r[cc][1].x, 1, 32);
        float l2 = __shfl_up(r[cc][2].w, 1, 32), h2 = __shfl_down(r[cc][2].x, 1, 32);
        float l3 = __shfl_up(r[cc][3].w, 1, 32), h3 = __shfl_down(r[cc][3].x, 1, 32);
        if (tx == 0)  { l0 = l1 = l2 = l3 = 0.f; }
        if (tx == 31) { h0 = h1 = h2 = h3 = 0.f; }

        f4 o0 = z4, o1 = z4;
        accum3(o0, l0, r[cc][0], h0, dA[0], dA[1], dA[2]);
        accum3(o0, l1, r[cc][1], h1, dA[3], dA[4], dA[5]);
        accum3(o0, l2, r[cc][2], h2, dA[6], dA[7], dA[8]);
        accum3(o1, l1, r[cc][1], h1, dB[0], dB[1], dB[2]);
        accum3(o1, l2, r[cc][2], h2, dB[3], dB[4], dB[5]);
        accum3(o1, l3, r[cc][3], h3, dB[6], dB[7], dB[8]);

        float* oC = oB + (size_t)c * (HH * WW) + x0;
        *reinterpret_cast<f4*>(oC + (size_t)(y0    ) * WW) = o0;
        *reinterpret_cast<f4*>(oC + (size_t)(y0 + 1) * WW) = o1;
    }
}

extern "C" void kernel_launch(void* const* d_in, const int* in_sizes, int n_in,
                              void* d_out, int out_size, void* d_ws, size_t ws_size,
                              hipStream_t stream)
{
    const float* Dot = (const float*)d_in[0];  // (16, 9, 128, 128)
    const float* V   = (const float*)d_in[1];  // (16, 64, 128, 128)
    float* out       = (float*)d_out;          // (16, 64, 128, 128)

    msa_conv2d_kernel<<<dim3(1024), 512, 0, stream>>>(Dot, V, out);
}

// Round 12
// 27.989 us; speedup vs baseline: 1.1253x; 1.1253x over previous
//
#include <hip/hip_runtime.h>

// out[b,c,y,x] = sum_{i,j} Dot[b,3i+j,y,x] * V[b,c,y+i-1,x+j-1]  (zero-padded)
// b=16, c=64, h=w=128, fp32. Traffic ideal (~103 MB); six structures pin at
// 27.8-33.7us. Last untested mechanism: per-block one-shot latency (4-8 block
// generations/CU, each a cold round-trip). This round: persistent streaming -
// each block owns 8 output rows, rolls a 4-row V window in registers across 4
// tiles, prefetches next tile's 2 rows before computing current; Dot for all
// 8 rows staged once via async global_load_lds (single barrier per block).

#define HH 128
#define WW 128
#define CC 64
#define KK 9
#define NT 4                 // tiles/block, 2 rows each -> 8-row y-block

typedef float f4 __attribute__((ext_vector_type(4)));

__device__ __forceinline__ void accum3(f4& o, float vl, const f4& vm, float vr,
                                       const f4& d0, const f4& d1, const f4& d2)
{
    o.x += d0.x * vl   + d1.x * vm.x + d2.x * vm.y;
    o.y += d0.y * vm.x + d1.y * vm.y + d2.y * vm.z;
    o.z += d0.z * vm.y + d1.z * vm.z + d2.z * vm.w;
    o.w += d0.w * vm.z + d1.w * vm.w + d2.w * vr;
}

__global__ __launch_bounds__(256) void msa_conv2d_kernel(
    const float* __restrict__ Dot,
    const float* __restrict__ V,
    float* __restrict__ out)
{
    __shared__ float dotS[8][KK][WW];   // 36864 B, 4 blocks/CU by LDS

    // 1024 blocks; XCD = n%8. XCD k owns L in [k*128,(k+1)*128):
    // L = ((b*16 + yb)*4 + chq) -> each XCD owns 2 whole batch images
    // (all y-blocks + all channel-quarters): Dot L2 reuse + V halo L2 reuse.
    const int n   = blockIdx.x;
    const int L   = (n & 7) * 128 + (n >> 3);
    const int b   = L >> 6;             // 0..15
    const int rem = L & 63;
    const int yb  = rem >> 2;           // 0..15
    const int chq = rem & 3;            // 0..3
    const int yB  = yb * 8;             // base output row

    const int tid = threadIdx.x;
    const int tx  = tid & 31;           // x-quad 0..31
    const int tc  = tid >> 5;           // 0..7
    const int x0  = tx * 4;

    const int c0 = chq * 16 + tc;       // two channels per thread
    const int c1 = c0 + 8;

    const float* vC0 = V + (((size_t)b * CC + c0) * HH) * WW + x0;
    const float* vC1 = V + (((size_t)b * CC + c1) * HH) * WW + x0;
    float*       oC0 = out + (((size_t)b * CC + c0) * HH) * WW + x0;
    float*       oC1 = out + (((size_t)b * CC + c1) * HH) * WW + x0;

    const f4 z4 = {0.f, 0.f, 0.f, 0.f};
    auto loadRow = [&](const float* base, int row) -> f4 {
        return (row >= 0 && row < HH)
             ? *reinterpret_cast<const f4*>(base + (size_t)row * WW) : z4;
    };

    // ---- Prologue 1: tile-0 V window (rows yB-1 .. yB+2), 8 loads in flight.
    f4 w0[4], w1[4];
    #pragma unroll
    for (int i = 0; i < 4; ++i) {
        w0[i] = loadRow(vC0, yB - 1 + i);
        w1[i] = loadRow(vC1, yB - 1 + i);
    }

    // ---- Prologue 2: async-stage Dot[b, :, yB..yB+7, :] to LDS.
    // 2304 16B-chunks, 9 rounds x 256 threads; dest linear in t
    // (wave-uniform base + lane*16 requirement satisfied).
    {
        float* ldsBase = &dotS[0][0][0];
        #pragma unroll
        for (int rnd = 0; rnd < 9; ++rnd) {
            const int t  = tid + rnd * 256;
            const int yy = t / 288;           // 288 chunks per y-row
            const int rm = t - yy * 288;
            const int k  = rm >> 5;
            const int x4 = rm & 31;
            const float* src = Dot + (((size_t)b * KK + k) * HH + (yB + yy)) * WW + x4 * 4;
            __builtin_amdgcn_global_load_lds(
                (const __attribute__((address_space(1))) void*)src,
                (__attribute__((address_space(3))) void*)(ldsBase + (size_t)t * 4),
                16, 0, 0);
        }
    }
    __syncthreads();   // drains staging + tile-0 window together

    // ---- Steady state: 4 tiles, prefetch t+1 under compute of t.
    #pragma unroll
    for (int t = 0; t < NT; ++t) {
        const int y0 = yB + t * 2;

        f4 p00 = z4, p01 = z4, p10 = z4, p11 = z4;
        if (t < NT - 1) {                 // prefetch rows y0+3, y0+4
            p00 = loadRow(vC0, y0 + 3);
            p01 = loadRow(vC0, y0 + 4);
            p10 = loadRow(vC1, y0 + 3);
            p11 = loadRow(vC1, y0 + 4);
        }

        // Halos for the 4 window rows (per channel).
        float l0[4], h0[4], l1[4], h1[4];
        #pragma unroll
        for (int i = 0; i < 4; ++i) {
            l0[i] = __shfl_up(w0[i].w, 1, 32);  h0[i] = __shfl_down(w0[i].x, 1, 32);
            l1[i] = __shfl_up(w1[i].w, 1, 32);  h1[i] = __shfl_down(w1[i].x, 1, 32);
        }
        if (tx == 0) {
            #pragma unroll
            for (int i = 0; i < 4; ++i) { l0[i] = 0.f; l1[i] = 0.f; }
        }
        if (tx == 31) {
            #pragma unroll
            for (int i = 0; i < 4; ++i) { h0[i] = 0.f; h1[i] = 0.f; }
        }

        // Output row y0 (weights dA, transient 9 f4; shared by both channels).
        {
            f4 dA[KK];
            #pragma unroll
            for (int k = 0; k < KK; ++k)
                dA[k] = *reinterpret_cast<const f4*>(&dotS[t * 2][k][x0]);

            f4 oA0 = z4, oA1 = z4;
            accum3(oA0, l0[0], w0[0], h0[0], dA[0], dA[1], dA[2]);
            accum3(oA0, l0[1], w0[1], h0[1], dA[3], dA[4], dA[5]);
            accum3(oA0, l0[2], w0[2], h0[2], dA[6], dA[7], dA[8]);
            accum3(oA1, l1[0], w1[0], h1[0], dA[0], dA[1], dA[2]);
            accum3(oA1, l1[1], w1[1], h1[1], dA[3], dA[4], dA[5]);
            accum3(oA1, l1[2], w1[2], h1[2], dA[6], dA[7], dA[8]);
            *reinterpret_cast<f4*>(oC0 + (size_t)y0 * WW) = oA0;
            *reinterpret_cast<f4*>(oC1 + (size_t)y0 * WW) = oA1;
        }

        // Output row y0+1 (weights dB).
        {
            f4 dB[KK];
            #pragma unroll
            for (int k = 0; k < KK; ++k)
                dB[k] = *reinterpret_cast<const f4*>(&dotS[t * 2 + 1][k][x0]);

            f4 oB0 = z4, oB1 = z4;
            accum3(oB0, l0[1], w0[1], h0[1], dB[0], dB[1], dB[2]);
            accum3(oB0, l0[2], w0[2], h0[2], dB[3], dB[4], dB[5]);
            accum3(oB0, l0[3], w0[3], h0[3], dB[6], dB[7], dB[8]);
            accum3(oB1, l1[1], w1[1], h1[1], dB[0], dB[1], dB[2]);
            accum3(oB1, l1[2], w1[2], h1[2], dB[3], dB[4], dB[5]);
            accum3(oB1, l1[3], w1[3], h1[3], dB[6], dB[7], dB[8]);
            *reinterpret_cast<f4*>(oC0 + (size_t)(y0 + 1) * WW) = oB0;
            *reinterpret_cast<f4*>(oC1 + (size_t)(y0 + 1) * WW) = oB1;
        }

        // Rotate window (static, renamed by unroll).
        if (t < NT - 1) {
            w0[0] = w0[2]; w0[1] = w0[3]; w0[2] = p00; w0[3] = p01;
            w1[0] = w1[2]; w1[1] = w1[3]; w1[2] = p10; w1[3] = p11;
        }
    }
}

extern "C" void kernel_launch(void* const* d_in, const int* in_sizes, int n_in,
                              void* d_out, int out_size, void* d_ws, size_t ws_size,
                              hipStream_t stream)
{
    const float* Dot = (const float*)d_in[0];  // (16, 9, 128, 128)
    const float* V   = (const float*)d_in[1];  // (16, 64, 128, 128)
    float* out       = (float*)d_out;          // (16, 64, 128, 128)

    msa_conv2d_kernel<<<dim3(1024), 256, 0, stream>>>(Dot, V, out);
}